// Round 6
// baseline (256.258 us; speedup 1.0000x reference)
//
#include <hip/hip_runtime.h>
#include <math.h>

namespace {
constexpr int K = 16, T = 8, R = 8, NB = 32;
constexpr int NX = 64, NY = 64, NZ = 32;
constexpr int NVOX = NX * NY * NZ;                 // 131072
constexpr float TWO_PI_OVER_C = (float)(6.283185307179586 / 299792458.0);
constexpr float CT_SCALE = 4.0f / 256.0f;          // scale split across Ht,Hr; cancels in normalize
constexpr float CR_SCALE = 1.0f / 256.0f;
// B table: [tr(64)][out(2)][quad(4)][n(32)][j(8)] halves = 262144 B
constexpr int B_HALVES = 64 * 2 * 4 * 32 * 8;      // 131072
constexpr size_t WS_NEED = 256 + (size_t)B_HALVES * 2;
}

typedef _Float16 half8 __attribute__((ext_vector_type(8)));
typedef __fp16 fp16x2 __attribute__((ext_vector_type(2)));   // cvt_pkrtz native type
typedef float f32x4 __attribute__((ext_vector_type(4)));

// ---------------------------------------------------------------------------
// Prep: zero max slot; build B fragments in ws.
// B[k'][n] per (tr, out):  k'<16 -> (out0: yre, out1: yim),  k'>=16 -> (out0: -yim, out1: yre)
// ---------------------------------------------------------------------------
__global__ void prep_kernel(const float* __restrict__ yr, const float* __restrict__ yi,
                            _Float16* __restrict__ wsB, unsigned int* __restrict__ maxslot,
                            int use_ws) {
    int id = blockIdx.x * 256 + threadIdx.x;   // 16384 threads
    if (id == 0) *maxslot = 0u;
    if (!use_ws || id >= 64 * 2 * 4 * 32) return;
    int n    = id & 31;
    int quad = (id >> 5) & 3;
    int outc = (id >> 7) & 1;
    int tr   = id >> 8;
    int t = tr >> 3, r = tr & 7;
    bool second = quad >= 2;                    // k' >= 16 half (pairs with AIm)
    const float* src = (outc == 0) ? (second ? yi : yr) : (second ? yr : yi);
    float sg = (outc == 0 && second) ? -1.0f : 1.0f;
    int base = n * (K * T * R) + ((quad & 1) * 8) * (T * R) + t * R + r;
    half8 h;
#pragma unroll
    for (int j = 0; j < 8; ++j)
        h[j] = (_Float16)(sg * src[base + j * (T * R)]);
    ((half8*)wsB)[id] = h;
}

// ---------------------------------------------------------------------------
// Main: per wave, 16-voxel x 32-batch complex tile via MFMA.
// A = 4*Ht*Hr: Hr built in LDS once per block, hoisted into fp16 VGPRs
// (X[r], Y[r], sign pre-applied). Ht per t kept in fp32 registers.
// A elements computed in fp32 via v_fma_mix (fp16 operands promoted exactly,
// fp32 accumulate -> no cancellation amplification), single fp16 rounding.
// Inner loop: ~20 VALU + 4 MFMA + depth-2 register-pipelined B loads.
// ---------------------------------------------------------------------------
template <bool USE_WS>
__global__ __launch_bounds__(256, 3) void kirch_mfma(
    const float* __restrict__ freqs,
    const float* __restrict__ txp, const float* __restrict__ rxp,
    const float* __restrict__ xc, const float* __restrict__ yc, const float* __restrict__ zc,
    const _Float16* __restrict__ wsB,
    const float* __restrict__ yr, const float* __restrict__ yi,
    float* __restrict__ out, unsigned int* __restrict__ maxslot)
{
    __shared__ _Float16 sHrRe[8][2][64][8];   // [r][kh][vox][j]  16 KB
    __shared__ _Float16 sHrIm[8][2][64][8];   // 16 KB
    __shared__ float s_wmax[4];

    const int tid  = threadIdx.x;
    const int lane = tid & 63;
    const int wave = tid >> 6;
    const int nlo  = lane & 15;
    const int quad = lane >> 4;
    const int kh   = quad & 1;
    const int vb   = blockIdx.x * 64 + wave * 16;
    const int v    = vb + nlo;                 // this lane's voxel (fragment row m)
    const int bv2  = wave * 16 + nlo;          // block-local voxel index

    const float k0 = TWO_PI_OVER_C * freqs[0];
    const float dk = TWO_PI_OVER_C * (freqs[K - 1] - freqs[0]) * (1.0f / (K - 1));

    // ---- Phase 1: cooperatively build Hr table (64 vox x 8 r x 16 k) ----
#pragma unroll
    for (int s = 0; s < 2; ++s) {
        int task = tid + (s << 8);             // 512 tasks
        int bv = task & 63;
        int r  = task >> 6;
        int gv = blockIdx.x * 64 + bv;
        float qx = xc[gv >> 11];
        float qy = yc[(gv >> 5) & 63];
        float qz = zc[gv & 31];
        float rxx = rxp[r * 3 + 0], rxy = rxp[r * 3 + 1], rxz = rxp[r * 3 + 2];
        float dx = qx - rxx, dy = qy - rxy, dz = qz - rxz;
        float Rr = sqrtf(dx * dx + dy * dy + dz * dz);
        float c = CR_SCALE * dz * __builtin_amdgcn_rcpf(Rr);
        float sph, cph, swp, cwp;
        __sincosf(k0 * Rr, &sph, &cph);
        __sincosf(dk * Rr, &swp, &cwp);
        float ur = cph, ui = sph;
        float ck = c * (k0 * Rr);
        const float dck = c * (dk * Rr);
        float re[16], im[16];
#pragma unroll
        for (int kk = 0; kk < 16; ++kk) {
            re[kk] = fmaf(c, ur, -(ck * ui));   // c*(ur - kR*ui)
            im[kk] = fmaf(c, ui,  (ck * ur));   // c*(ui + kR*ur)
            float nr = fmaf(ur, cwp, -(ui * swp));
            ui = fmaf(ur, swp, ui * cwp);
            ur = nr;
            ck += dck;
        }
        union { half8 v8; fp16x2 v2[4]; } h;
#pragma unroll
        for (int kk2 = 0; kk2 < 2; ++kk2) {
#pragma unroll
            for (int i = 0; i < 4; ++i)
                h.v2[i] = __builtin_amdgcn_cvt_pkrtz(re[kk2 * 8 + 2 * i], re[kk2 * 8 + 2 * i + 1]);
            *(half8*)&sHrRe[r][kk2][bv][0] = h.v8;
#pragma unroll
            for (int i = 0; i < 4; ++i)
                h.v2[i] = __builtin_amdgcn_cvt_pkrtz(im[kk2 * 8 + 2 * i], im[kk2 * 8 + 2 * i + 1]);
            *(half8*)&sHrIm[r][kk2][bv][0] = h.v8;
        }
    }
    __syncthreads();

    // ---- hoist Hr into registers: X[r], Y[r] (sign pre-applied, fp16) ----
    // Re-quads: A = HtRe*HrRe - HtIm*HrIm  -> X=HrRe, Y=-HrIm
    // Im-quads: A = HtRe*HrIm + HtIm*HrRe  -> X=HrIm, Y= HrRe
    const _Float16* pX = (quad < 2) ? &sHrRe[0][kh][bv2][0] : &sHrIm[0][kh][bv2][0];
    const _Float16* pZ = (quad < 2) ? &sHrIm[0][kh][bv2][0] : &sHrRe[0][kh][bv2][0];
    const unsigned int sgn = (quad < 2) ? 0x80008000u : 0u;
    half8 Xr[8], Yr[8];
#pragma unroll
    for (int r = 0; r < R; ++r) {
        Xr[r] = *(const half8*)(pX + r * 1024);
        union { half8 h; unsigned int u[4]; } Z;
        Z.h = *(const half8*)(pZ + r * 1024);
#pragma unroll
        for (int i = 0; i < 4; ++i) Z.u[i] ^= sgn;
        Yr[r] = Z.h;
    }

    // ---- per-lane constants ----
    const float px = xc[v >> 11];
    const float py = yc[(v >> 5) & 63];
    const float pz = zc[v & 31];
    const float kstart = k0 + (kh ? 8.0f * dk : 0.0f);

    f32x4 accRe0 = {0,0,0,0}, accRe1 = {0,0,0,0};
    f32x4 accIm0 = {0,0,0,0}, accIm1 = {0,0,0,0};

    // ---- B load pipeline: depth-2 register ping-pong, uniform stride ----
    half8 pb[2][4];
    const char* bptr = (const char*)wsB + quad * 512 + nlo * 16;  // +=4096 per tr
    int tr_issue = 0;
    auto issueB = [&](int slot) {
        if (USE_WS) {
            pb[slot][0] = *(const half8*)(bptr);             // Re-out, ntile 0
            pb[slot][1] = *(const half8*)(bptr + 256);       // Re-out, ntile 1
            pb[slot][2] = *(const half8*)(bptr + 2048);      // Im-out, ntile 0
            pb[slot][3] = *(const half8*)(bptr + 2304);      // Im-out, ntile 1
            bptr += 4096;
        } else {
            const int tr = tr_issue;
            const int kb = kh * 8;
            const float* sA = (quad < 2) ? yr : yi;
            const float sgA = (quad < 2) ? 1.0f : -1.0f;
            const float* sB = (quad < 2) ? yi : yr;
            auto gather = [&](const float* src, float sg, int n) {
                int base = n * (K * T * R) + kb * (T * R) + tr;
                half8 h;
#pragma unroll
                for (int j = 0; j < 8; ++j) h[j] = (_Float16)(sg * src[base + j * (T * R)]);
                return h;
            };
            pb[slot][0] = gather(sA, sgA, nlo);
            pb[slot][1] = gather(sA, sgA, 16 + nlo);
            pb[slot][2] = gather(sB, 1.0f, nlo);
            pb[slot][3] = gather(sB, 1.0f, 16 + nlo);
        }
        ++tr_issue;
    };
    issueB(0);   // tr 0
    issueB(1);   // tr 1

    for (int t = 0; t < T; ++t) {
        // ---- Ht for this (voxel, t) over the lane's 8 freqs — kept in fp32 ----
        const float txx = txp[t * 3 + 0], txy = txp[t * 3 + 1], txz = txp[t * 3 + 2];
        const float dxt = px - txx, dyt = py - txy, dzt = pz - txz;
        const float Rt = sqrtf(dxt * dxt + dyt * dyt + dzt * dzt);
        const float c = CT_SCALE * dzt * __builtin_amdgcn_rcpf(Rt);
        float sph, cph, swp, cwp;
        __sincosf(kstart * Rt, &sph, &cph);
        __sincosf(dk * Rt, &swp, &cwp);
        float ur = cph, ui = sph;
        float ck = c * (kstart * Rt);
        const float dck = c * (dk * Rt);
        float hre[8], him[8];
#pragma unroll
        for (int j = 0; j < 8; ++j) {
            hre[j] = fmaf(c, ur, -(ck * ui));
            him[j] = fmaf(c, ui,  (ck * ur));
            if (j < 7) {
                float nr = fmaf(ur, cwp, -(ui * swp));
                ui = fmaf(ur, swp, ui * cwp);
                ur = nr;
                ck += dck;
            }
        }

#pragma unroll
        for (int r = 0; r < R; ++r) {
            const int slot = r & 1;            // (t*8+r)&1, t*8 even
            // A fragment: fp32 mixed-precision complex product (v_fma_mix),
            // single fp16 rounding at the end.
            half8 X = Xr[r], Y = Yr[r];
            float vals[8];
#pragma unroll
            for (int j = 0; j < 8; ++j)
                vals[j] = fmaf(hre[j], (float)X[j], him[j] * (float)Y[j]);
            union { half8 v8; fp16x2 v2[4]; } A;
#pragma unroll
            for (int i = 0; i < 4; ++i)
                A.v2[i] = __builtin_amdgcn_cvt_pkrtz(vals[2 * i], vals[2 * i + 1]);

            half8 b0 = pb[slot][0], b1 = pb[slot][1], b2 = pb[slot][2], b3 = pb[slot][3];
            if (t * 8 + r < 62) issueB(slot);  // keep 2 tr in flight (wave-uniform branch)
            accRe0 = __builtin_amdgcn_mfma_f32_16x16x32_f16(A.v8, b0, accRe0, 0, 0, 0);
            accRe1 = __builtin_amdgcn_mfma_f32_16x16x32_f16(A.v8, b1, accRe1, 0, 0, 0);
            accIm0 = __builtin_amdgcn_mfma_f32_16x16x32_f16(A.v8, b2, accIm0, 0, 0, 0);
            accIm1 = __builtin_amdgcn_mfma_f32_16x16x32_f16(A.v8, b3, accIm1, 0, 0, 0);
        }
    }

    // ---- epilogue: magnitudes, store, block max ----
    // C/D layout: n = ntile*16 + (lane&15), m(voxel) = quad*4 + reg
    float mx = 0.0f;
#pragma unroll
    for (int reg = 0; reg < 4; ++reg) {
        const int vv = vb + quad * 4 + reg;
        float re0 = accRe0[reg], im0 = accIm0[reg];
        float m0 = sqrtf(re0 * re0 + im0 * im0);
        out[nlo * NVOX + vv] = m0;
        float re1 = accRe1[reg], im1 = accIm1[reg];
        float m1 = sqrtf(re1 * re1 + im1 * im1);
        out[(16 + nlo) * NVOX + vv] = m1;
        mx = fmaxf(mx, fmaxf(m0, m1));
    }
#pragma unroll
    for (int off = 32; off > 0; off >>= 1)
        mx = fmaxf(mx, __shfl_down(mx, off));
    if (lane == 0) s_wmax[wave] = mx;
    __syncthreads();
    if (threadIdx.x == 0) {
        float bm = fmaxf(fmaxf(s_wmax[0], s_wmax[1]), fmaxf(s_wmax[2], s_wmax[3]));
        atomicMax(maxslot, __float_as_uint(bm));
    }
}

// ---------------------------------------------------------------------------
// Normalize: out *= 1/max
// ---------------------------------------------------------------------------
__global__ void normalize_kernel(float* __restrict__ out,
                                 const unsigned int* __restrict__ maxslot, int n4) {
    int i = blockIdx.x * blockDim.x + threadIdx.x;
    float inv = 1.0f / __uint_as_float(*maxslot);
    if (i < n4) {
        float4* o = (float4*)out;
        float4 vv = o[i];
        vv.x *= inv; vv.y *= inv; vv.z *= inv; vv.w *= inv;
        o[i] = vv;
    }
}

extern "C" void kernel_launch(void* const* d_in, const int* in_sizes, int n_in,
                              void* d_out, int out_size, void* d_ws, size_t ws_size,
                              hipStream_t stream) {
    const float* freqs = (const float*)d_in[0];
    const float* txp   = (const float*)d_in[1];
    const float* rxp   = (const float*)d_in[2];
    const float* xc    = (const float*)d_in[3];
    const float* yc    = (const float*)d_in[4];
    const float* zc    = (const float*)d_in[5];
    const float* yr    = (const float*)d_in[6];
    const float* yi    = (const float*)d_in[7];
    float* out = (float*)d_out;

    unsigned int* maxslot = (unsigned int*)d_ws;
    _Float16* wsB = (_Float16*)((char*)d_ws + 256);
    const int use_ws = (ws_size >= WS_NEED) ? 1 : 0;

    prep_kernel<<<64, 256, 0, stream>>>(yr, yi, wsB, maxslot, use_ws);

    if (use_ws)
        kirch_mfma<true><<<NVOX / 64, 256, 0, stream>>>(
            freqs, txp, rxp, xc, yc, zc, wsB, yr, yi, out, maxslot);
    else
        kirch_mfma<false><<<NVOX / 64, 256, 0, stream>>>(
            freqs, txp, rxp, xc, yc, zc, wsB, yr, yi, out, maxslot);

    int n4 = out_size / 4;
    normalize_kernel<<<(n4 + 255) / 256, 256, 0, stream>>>(out, maxslot, n4);
}